// Round 10
// baseline (1149.409 us; speedup 1.0000x reference)
//
#include <hip/hip_runtime.h>

// GRUModel: 2-layer GRU (H=64), B=4096, T=512, fp32 in/out — round 10 "duet".
//
// 256 blocks x 128 threads (2 waves). NO N-split, NO barriers in the loop:
//   wave 0 = complete layer 0 for 16 rows (24 MFMA/step), own h0 recurrence
//            through a private LDS ring (in-order per-wave DS pipe, R7-verified);
//   wave 1 = complete layer 1 (48 MFMA/step), own h1 via private plane.
// Only coupling: one-directional h0 ring (depth 4) + one flag each way
// (data flag prog0, back-pressure flag prog1). Producer runs ahead, so
// consumer polls are almost always pre-satisfied — unlike R9's same-step
// lockstep waits. Math identical to R8 -> absmax must be 4.8828e-4 exactly.
//
// Row placement: 16 real rows = full M of the 16x16x32 tile (zero MFMA waste).
// C-layout lane (q,n) owns rows 4q+r, units 16v+n -> 16 gate cells/lane.
//
// Frag layouts (m89/m120-verified):
//   A: lane holds A[m=lane&15][k=(lane>>4)*8+j], j=0..7
//   B: lane holds B[k=(lane>>4)*8+j][n=lane&15]
//   C/D: lane holds D[m=(lane>>4)*4+reg][n=lane&15]

typedef _Float16 half8 __attribute__((ext_vector_type(8)));
typedef float    v4f   __attribute__((ext_vector_type(4)));

#define T_LEN 512
#define KS 72            // fp16 row stride of h planes (16B-aligned b128 reads)
#define PLANE (16 * KS)

static __device__ __forceinline__ float sigm(float x) {
    return 1.0f / (1.0f + __expf(-x));
}
static __device__ __forceinline__ float tanh_fast(float x) {
    return 2.0f / (1.0f + __expf(-2.0f * x)) - 1.0f;
}
static __device__ __forceinline__ v4f mfma16(half8 a, half8 b, v4f c) {
    return __builtin_amdgcn_mfma_f32_16x16x32_f16(a, b, c, 0, 0, 0);
}
static __device__ __forceinline__ half8 ld8(const _Float16* p) {
    return *(const half8*)p;
}
// spin until *f >= need (producer is usually ahead -> first poll passes)
static __device__ __forceinline__ void wait_ge(volatile int* f, int need) {
    if (need <= 0) return;
    int guard = 0;
    while (*f < need) { if (++guard > (1 << 24)) break; }
    __builtin_amdgcn_fence(__ATOMIC_ACQUIRE, "workgroup");
}
// release-publish: in-order per-wave DS pipe => flag lands after data stores
static __device__ __forceinline__ void publish(volatile int* f, int val, int lane) {
    __builtin_amdgcn_fence(__ATOMIC_RELEASE, "workgroup");
    if (lane == 0) *f = val;
}

__global__ __launch_bounds__(128, 1)
void gru_duet(const float* __restrict__ x,
              const float* __restrict__ w_ih0, const float* __restrict__ w_hh0,
              const float* __restrict__ b_ih0, const float* __restrict__ b_hh0,
              const float* __restrict__ w_ih1, const float* __restrict__ w_hh1,
              const float* __restrict__ b_ih1, const float* __restrict__ b_hh1,
              const float* __restrict__ fc_w,  const float* __restrict__ fc_b,
              float* __restrict__ out)
{
    __shared__ __align__(16) float xs[T_LEN * 16];        // [t][m], 32 KB
    __shared__ __align__(16) _Float16 ring[4][PLANE];     // h0 ring, 9 KB
    __shared__ __align__(16) _Float16 h1p[PLANE];         // wave-1 private h1
    __shared__ int prog[2];                               // [0]=L0 steps, [1]=L1

    const int tid  = threadIdx.x;
    const int wv   = tid >> 6;
    const int lane = tid & 63;
    const int n    = lane & 15;
    const int q    = lane >> 4;

    // ---- stage 16 x-rows into LDS as [t][m] (coalesced over t) ----
    const float* xg = x + (size_t)(blockIdx.x * 16) * T_LEN;
    for (int i = tid; i < 16 * T_LEN; i += 128) {
        const int row = i >> 9, t = i & 511;
        xs[t * 16 + row] = xg[row * T_LEN + t];
    }
    for (int i = tid; i < 4 * PLANE; i += 128) ((_Float16*)ring)[i] = (_Float16)0;
    for (int i = tid; i < PLANE; i += 128) h1p[i] = (_Float16)0;
    if (tid < 2) prog[tid] = 0;

    __syncthreads();   // the only block-wide sync before the epilogue

    const int ab = n * KS + 8 * q;        // A-frag base (fp16 elems)
    const int wb = (4 * q) * KS + n;      // write base (row 4q+r at +r*KS, +16v)

    volatile int* p0 = &prog[0];
    volatile int* p1 = &prog[1];

    if (wv == 0) {
        // ================= wave 0: complete layer 0 =================
        half8 B0[3][4][2];   // [gate][vgroup][chunk], W_hh0 K=64
        #pragma unroll
        for (int g = 0; g < 3; g++)
            #pragma unroll
            for (int v = 0; v < 4; v++)
                #pragma unroll
                for (int c = 0; c < 2; c++) {
                    const float* r0 = w_hh0 + (g * 64 + 16 * v + n) * 64 + 32 * c + 8 * q;
                    #pragma unroll
                    for (int j = 0; j < 8; j++) B0[g][v][c][j] = (_Float16)r0[j];
                }
        float wir[4], wiz[4], win[4], br0[4], bz0[4], bin0[4], bhn0[4];
        #pragma unroll
        for (int v = 0; v < 4; v++) {
            const int u = 16 * v + n;
            wir[v] = w_ih0[u]; wiz[v] = w_ih0[64 + u]; win[v] = w_ih0[128 + u];
            br0[v] = b_ih0[u] + b_hh0[u];
            bz0[v] = b_ih0[64 + u] + b_hh0[64 + u];
            bin0[v] = b_ih0[128 + u]; bhn0[v] = b_hh0[128 + u];
        }
        v4f zero4; zero4[0] = 0.f; zero4[1] = 0.f; zero4[2] = 0.f; zero4[3] = 0.f;
        float hst[4][4];
        #pragma unroll
        for (int v = 0; v < 4; v++)
            #pragma unroll
            for (int r = 0; r < 4; r++) hst[v][r] = 0.f;

        #pragma unroll 1
        for (int t = 0; t < T_LEN; t++) {
            wait_ge(p1, t - 3);             // ring slot t%4 free (L1 done t-4)
            const int sr = (t - 1) & 3, sw = t & 3;
            const half8 a0 = ld8(&ring[sr][ab]);         // own writes, in-order DS
            const half8 a1 = ld8(&ring[sr][ab + 32]);
            const v4f xv = *(const v4f*)(xs + t * 16 + 4 * q);

            v4f aR[4], aZ[4], aN[4];
            #pragma unroll
            for (int v = 0; v < 4; v++) {
                #pragma unroll
                for (int r = 0; r < 4; r++) {
                    aR[v][r] = fmaf(xv[r], wir[v], br0[v]);
                    aZ[v][r] = fmaf(xv[r], wiz[v], bz0[v]);
                }
                aN[v] = mfma16(a0, B0[2][v][0], zero4);
                aR[v] = mfma16(a0, B0[0][v][0], aR[v]);
                aZ[v] = mfma16(a0, B0[1][v][0], aZ[v]);
                aN[v] = mfma16(a1, B0[2][v][1], aN[v]);
                aR[v] = mfma16(a1, B0[0][v][1], aR[v]);
                aZ[v] = mfma16(a1, B0[1][v][1], aZ[v]);
            }
            #pragma unroll
            for (int v = 0; v < 4; v++)
                #pragma unroll
                for (int r = 0; r < 4; r++) {
                    const float rg = sigm(aR[v][r]);
                    const float zg = sigm(aZ[v][r]);
                    const float inn = fmaf(xv[r], win[v], bin0[v]);
                    const float ng = tanh_fast(inn + rg * (aN[v][r] + bhn0[v]));
                    const float h = ng + zg * (hst[v][r] - ng);
                    hst[v][r] = h;
                    ring[sw][wb + r * KS + 16 * v] = (_Float16)h;
                }
            publish(p0, t + 1, lane);
        }
    } else {
        // ================= wave 1: complete layer 1 =================
        half8 B1[3][4][4];   // [gate][vgroup][chunk], c<2: W_ih1, c>=2: W_hh1
        #pragma unroll
        for (int g = 0; g < 3; g++)
            #pragma unroll
            for (int v = 0; v < 4; v++)
                #pragma unroll
                for (int c = 0; c < 4; c++) {
                    const float* M = (c < 2) ? w_ih1 : w_hh1;
                    const float* r0 = M + (g * 64 + 16 * v + n) * 64 + 32 * (c & 1) + 8 * q;
                    #pragma unroll
                    for (int j = 0; j < 8; j++) B1[g][v][c][j] = (_Float16)r0[j];
                }
        // persistent bias vectors as MFMA C-operands (no per-step acc init)
        v4f bR[4], bZ[4], bNi[4], bNh[4];
        #pragma unroll
        for (int v = 0; v < 4; v++) {
            const int u = 16 * v + n;
            const float r_ = b_ih1[u] + b_hh1[u];
            const float z_ = b_ih1[64 + u] + b_hh1[64 + u];
            const float ni = b_ih1[128 + u];
            const float nh = b_hh1[128 + u];
            #pragma unroll
            for (int r = 0; r < 4; r++) { bR[v][r] = r_; bZ[v][r] = z_; bNi[v][r] = ni; bNh[v][r] = nh; }
        }
        float hst[4][4];
        #pragma unroll
        for (int v = 0; v < 4; v++)
            #pragma unroll
            for (int r = 0; r < 4; r++) hst[v][r] = 0.f;

        #pragma unroll 1
        for (int s = 0; s < T_LEN; s++) {
            wait_ge(p0, s + 1);             // h0(s) published (producer ahead)
            const int s0 = s & 3;
            const half8 g00 = ld8(&ring[s0][ab]);        // h0(s)
            const half8 g01 = ld8(&ring[s0][ab + 32]);
            const half8 g10 = ld8(&h1p[ab]);             // h1(s-1), own in-order
            const half8 g11 = ld8(&h1p[ab + 32]);

            v4f aR[4], aZ[4], aNi[4], aNh[4];
            #pragma unroll
            for (int v = 0; v < 4; v++) {
                aR[v]  = mfma16(g00, B1[0][v][0], bR[v]);
                aZ[v]  = mfma16(g00, B1[1][v][0], bZ[v]);
                aNi[v] = mfma16(g00, B1[2][v][0], bNi[v]);
                aNh[v] = mfma16(g10, B1[2][v][2], bNh[v]);
                aR[v]  = mfma16(g01, B1[0][v][1], aR[v]);
                aZ[v]  = mfma16(g01, B1[1][v][1], aZ[v]);
                aNi[v] = mfma16(g01, B1[2][v][1], aNi[v]);
                aNh[v] = mfma16(g11, B1[2][v][3], aNh[v]);
                aR[v]  = mfma16(g10, B1[0][v][2], aR[v]);
                aZ[v]  = mfma16(g10, B1[1][v][2], aZ[v]);
                aR[v]  = mfma16(g11, B1[0][v][3], aR[v]);
                aZ[v]  = mfma16(g11, B1[1][v][3], aZ[v]);
            }
            #pragma unroll
            for (int v = 0; v < 4; v++)
                #pragma unroll
                for (int r = 0; r < 4; r++) {
                    const float rg = sigm(aR[v][r]);
                    const float zg = sigm(aZ[v][r]);
                    const float ng = tanh_fast(aNi[v][r] + rg * aNh[v][r]);
                    const float h = ng + zg * (hst[v][r] - ng);
                    hst[v][r] = h;
                    h1p[wb + r * KS + 16 * v] = (_Float16)h;
                }
            publish(p1, s + 1, lane);
        }

        // ==== FC epilogue: out[4q+r] = sum_u fc_w[u] h1[4q+r][u] + fc_b ====
        float fw[4];
        #pragma unroll
        for (int v = 0; v < 4; v++) fw[v] = fc_w[16 * v + n];
        const float fb = fc_b[0];
        #pragma unroll
        for (int r = 0; r < 4; r++) {
            float sacc = 0.f;
            #pragma unroll
            for (int v = 0; v < 4; v++) sacc = fmaf(fw[v], hst[v][r], sacc);
            sacc += __shfl_xor(sacc, 1, 64);
            sacc += __shfl_xor(sacc, 2, 64);
            sacc += __shfl_xor(sacc, 4, 64);
            sacc += __shfl_xor(sacc, 8, 64);   // reduce over 16 n-lanes
            if (n == 0) out[blockIdx.x * 16 + 4 * q + r] = sacc + fb;
        }
    }
}

extern "C" void kernel_launch(void* const* d_in, const int* in_sizes, int n_in,
                              void* d_out, int out_size, void* d_ws, size_t ws_size,
                              hipStream_t stream)
{
    const float* x     = (const float*)d_in[0];
    const float* w_ih0 = (const float*)d_in[1];
    const float* w_hh0 = (const float*)d_in[2];
    const float* b_ih0 = (const float*)d_in[3];
    const float* b_hh0 = (const float*)d_in[4];
    const float* w_ih1 = (const float*)d_in[5];
    const float* w_hh1 = (const float*)d_in[6];
    const float* b_ih1 = (const float*)d_in[7];
    const float* b_hh1 = (const float*)d_in[8];
    const float* fc_w  = (const float*)d_in[9];
    const float* fc_b  = (const float*)d_in[10];
    float* out = (float*)d_out;

    hipLaunchKernelGGL(gru_duet, dim3(256), dim3(128), 0, stream,
                       x, w_ih0, w_hh0, b_ih0, b_hh0,
                       w_ih1, w_hh1, b_ih1, b_hh1, fc_w, fc_b, out);
}

// Round 11
// 470.334 us; speedup vs baseline: 2.4438x; 2.4438x over previous
//
#include <hip/hip_runtime.h>

// GRUModel: 2-layer GRU (H=64), B=4096, T=512, fp32 in/out — MFMA round 11.
//
// R11 = R8 (614us) with TRANS-MINIMAL gate math. Unified-theory calibration
// (R7: 192 trans/step -> 6070 cyc window; R10: 96 -> 5306; R8: 48 -> 2873)
// says v_exp_f32 / v_rcp_f32 / div cost ~32 cyc/wave64-instr: the kernel is
// transcendental-issue-bound. Changes (gate math only, rest identical):
//   - merged GRU cell (algebraically exact): A=e^-az, B=e^-2w, C=e^-ar,
//       h' = [A(1-B) + h(1+B)] / [(1+A)(1+B)],  w = ni + nh/(1+C)
//     -> 3 exp (was 3 exp + 3 divisions)
//   - reciprocals via magic-seed + 3 Newton (8 full-rate instr, rel ~4e-11)
//     instead of the precise-div / v_rcp trans path.
//
// Structure (R8): 256 blocks x 512 threads; waves 0-3 layer 0 @ window k,
// waves 4-7 layer 1 @ k-1; single fp16 MFMA operands; one barrier/window;
// parity double-buffered h planes; h-state fp32 in registers.
//
// Frag layouts (m89/m120-verified):
//   A: lane holds A[m=lane&15][k=(lane>>4)*8+j], j=0..7
//   B: lane holds B[k=(lane>>4)*8+j][n=lane&15]
//   C/D: lane holds D[m=(lane>>4)*4+reg][n=lane&15]

typedef _Float16 half8 __attribute__((ext_vector_type(8)));
typedef float    v4f   __attribute__((ext_vector_type(4)));

#define T_LEN 512
#define KS 72   // fp16 row stride of h planes (16B-aligned b128 reads)

static __device__ __forceinline__ v4f mfma16(half8 a, half8 b, v4f c) {
    return __builtin_amdgcn_mfma_f32_16x16x32_f16(a, b, c, 0, 0, 0);
}
static __device__ __forceinline__ half8 ld8(const _Float16* p) {
    return *(const half8*)p;
}
// full-rate reciprocal: magic seed + 3 Newton (err ~ seed^8 ~ 4e-11)
static __device__ __forceinline__ float rcp_fast(float d) {
    float y = __builtin_bit_cast(float, 0x7EF127EAu - __builtin_bit_cast(unsigned, d));
    y = y * (2.0f - d * y);
    y = y * (2.0f - d * y);
    y = y * (2.0f - d * y);
    return y;
}
// merged GRU cell: r=sigm(ar), z=sigm(az), n=tanh(ni + r*nh), h'=n+z*(h-n)
// == [A(1-B) + h(1+B)] / [(1+A)(1+B)]; A=e^-az, B=e^-2w, C=e^-ar, w=ni+nh/(1+C)
static __device__ __forceinline__ float gru_cell(float ar, float az,
                                                 float ni, float nh, float h) {
    const float C  = __expf(-ar);
    const float r  = rcp_fast(1.0f + C);
    const float w  = fmaf(r, nh, ni);
    const float A  = __expf(-az);
    const float Bv = __expf(-2.0f * w);
    const float num = fmaf(h, 1.0f + Bv, A * (1.0f - Bv));
    const float den = (1.0f + A) * (1.0f + Bv);
    return num * rcp_fast(den);
}

__global__ __launch_bounds__(512, 1)
void gru_mfma(const float* __restrict__ x,
              const float* __restrict__ w_ih0, const float* __restrict__ w_hh0,
              const float* __restrict__ b_ih0, const float* __restrict__ b_hh0,
              const float* __restrict__ w_ih1, const float* __restrict__ w_hh1,
              const float* __restrict__ b_ih1, const float* __restrict__ b_hh1,
              const float* __restrict__ fc_w,  const float* __restrict__ fc_b,
              float* __restrict__ out)
{
    __shared__ __align__(16) float xs[T_LEN * 16];        // [t][m], 32 KB
    __shared__ __align__(16) _Float16 h0f[2][16 * KS];    // h0 fp16, 2 parities
    __shared__ __align__(16) _Float16 h1f[2][16 * KS];    // h1 fp16, 2 parities
    __shared__ float red[64];

    const int tid  = threadIdx.x;
    const int wv   = tid >> 6;
    const int grp  = wv >> 2;       // 0 = layer-0 group, 1 = layer-1 group
    const int w    = wv & 3;        // N-split within group
    const int lane = tid & 63;
    const int n    = lane & 15;
    const int q    = lane >> 4;
    const int u    = w * 16 + n;    // unit owned in gate phase

    // ---- stage this block's 16 x-rows into LDS as [t][m] (coalesced) ----
    const float* xg = x + (size_t)(blockIdx.x * 16) * T_LEN;
    for (int i = tid; i < 16 * T_LEN; i += 512) {
        const int row = i >> 9, t = i & 511;
        xs[t * 16 + row] = xg[row * T_LEN + t];
    }
    // zero parity-1 buffers (read before first write)
    for (int i = tid; i < 16 * KS; i += 512) {
        h0f[1][i] = (_Float16)0;
        h1f[1][i] = (_Float16)0;
    }

    // ---- loop-invariant weight B-fragments (single fp16), group-specific ----
    // grp0 uses c=0,1 (W_hh0, K=64); grp1 uses c=0..3 ([W_ih1 | W_hh1], K=128)
    half8 B[3][4];
    {
        const int rows[3] = {u, 64 + u, 128 + u};
        const float* bc[4];
        if (grp == 0) {
            bc[0] = w_hh0;      bc[1] = w_hh0 + 32;
            bc[2] = w_hh0;      bc[3] = w_hh0 + 32;   // unused dups
        } else {
            bc[0] = w_ih1;      bc[1] = w_ih1 + 32;
            bc[2] = w_hh1;      bc[3] = w_hh1 + 32;
        }
        #pragma unroll
        for (int g = 0; g < 3; g++)
            #pragma unroll
            for (int c = 0; c < 4; c++) {
                const float* r0 = bc[c] + rows[g] * 64 + 8 * q;
                #pragma unroll
                for (int j = 0; j < 8; j++) B[g][c][j] = (_Float16)r0[j];
            }
    }

    // per-lane gate constants for unit u (group-specific)
    float wir = 0.f, wiz = 0.f, win = 0.f, brc = 0.f, bzc = 0.f, binc = 0.f, bhnc = 0.f;
    if (grp == 0) {
        wir = w_ih0[u]; wiz = w_ih0[64 + u]; win = w_ih0[128 + u];
        brc = b_ih0[u] + b_hh0[u];
        bzc = b_ih0[64 + u] + b_hh0[64 + u];
        binc = b_ih0[128 + u]; bhnc = b_hh0[128 + u];
    } else {
        brc = b_ih1[u] + b_hh1[u];
        bzc = b_ih1[64 + u] + b_hh1[64 + u];
        binc = b_ih1[128 + u]; bhnc = b_hh1[128 + u];
    }

    float hst[4] = {0.f, 0.f, 0.f, 0.f};   // fp32 h[m=4q+reg][u] (own layer)

    __syncthreads();

    const int abase = n * KS + 8 * q;       // A-frag base (fp16 elems)

    #pragma unroll 1
    for (int k = 0; k < T_LEN + 1; k++) {
        if (grp == 0) {
            if (k < T_LEN) {
                const int pw = k & 1, pr = pw ^ 1;
                // A-frags of h0(k-1) — written @k-1 pre-barrier, visible now
                const half8 a0 = ld8(&h0f[pr][abase]);
                const half8 a1 = ld8(&h0f[pr][abase + 32]);
                const v4f xv = *(const v4f*)(xs + k * 16 + 4 * q);  // broadcast

                v4f accR, accZ, accN;
                #pragma unroll
                for (int r = 0; r < 4; r++) {
                    accR[r] = fmaf(xv[r], wir, brc);
                    accZ[r] = fmaf(xv[r], wiz, bzc);
                    accN[r] = 0.f;
                }
                accR = mfma16(a0, B[0][0], accR);
                accZ = mfma16(a0, B[1][0], accZ);
                accN = mfma16(a0, B[2][0], accN);
                accR = mfma16(a1, B[0][1], accR);
                accZ = mfma16(a1, B[1][1], accZ);
                accN = mfma16(a1, B[2][1], accN);

                #pragma unroll
                for (int r = 0; r < 4; r++) {
                    const float inn = fmaf(xv[r], win, binc);
                    const float h = gru_cell(accR[r], accZ[r],
                                             inn, accN[r] + bhnc, hst[r]);
                    hst[r] = h;
                    h0f[pw][(4 * q + r) * KS + u] = (_Float16)h;
                }
            }
        } else {
            if (k > 0) {
                const int t = k - 1;
                const int pw = t & 1;       // h0(t) parity; h1(t) write parity
                const int p1 = pw ^ 1;      // h1(t-1) parity
                const half8 g00 = ld8(&h0f[pw][abase]);        // h0new(t)
                const half8 g01 = ld8(&h0f[pw][abase + 32]);
                const half8 g10 = ld8(&h1f[p1][abase]);        // h1(t-1)
                const half8 g11 = ld8(&h1f[p1][abase + 32]);

                v4f aR, aZ, aNi, aNh;
                #pragma unroll
                for (int r = 0; r < 4; r++) {
                    aR[r] = brc;  aZ[r] = bzc;  aNi[r] = binc;  aNh[r] = bhnc;
                }
                // r,z fold i-side and h-side into one acc; n keeps them apart
                aR  = mfma16(g00, B[0][0], aR);
                aZ  = mfma16(g00, B[1][0], aZ);
                aNi = mfma16(g00, B[2][0], aNi);
                aNh = mfma16(g10, B[2][2], aNh);
                aR  = mfma16(g01, B[0][1], aR);
                aZ  = mfma16(g01, B[1][1], aZ);
                aNi = mfma16(g01, B[2][1], aNi);
                aNh = mfma16(g11, B[2][3], aNh);
                aR  = mfma16(g10, B[0][2], aR);
                aZ  = mfma16(g10, B[1][2], aZ);
                aR  = mfma16(g11, B[0][3], aR);
                aZ  = mfma16(g11, B[1][3], aZ);

                #pragma unroll
                for (int r = 0; r < 4; r++) {
                    const float h = gru_cell(aR[r], aZ[r],
                                             aNi[r], aNh[r], hst[r]);
                    hst[r] = h;
                    h1f[pw][(4 * q + r) * KS + u] = (_Float16)h;
                }
            }
        }
        __syncthreads();   // the ONE barrier per window (anti-dependence)
    }

    // ======== FC epilogue: out[m] = sum_u fc_w[u] h1[m][u] + fc_b ========
    if (grp == 1) {
        const float fw = fc_w[u];
        #pragma unroll
        for (int r = 0; r < 4; r++) {
            float v = fw * hst[r];
            v += __shfl_xor(v, 1, 64);
            v += __shfl_xor(v, 2, 64);
            v += __shfl_xor(v, 4, 64);
            v += __shfl_xor(v, 8, 64);   // sum over 16 n-lanes (q preserved)
            if (n == 0) red[(4 * q + r) * 4 + w] = v;
        }
    }
    __syncthreads();
    if (tid < 16) {
        const float s = red[tid * 4] + red[tid * 4 + 1] + red[tid * 4 + 2] + red[tid * 4 + 3];
        out[blockIdx.x * 16 + tid] = s + fc_b[0];
    }
}

extern "C" void kernel_launch(void* const* d_in, const int* in_sizes, int n_in,
                              void* d_out, int out_size, void* d_ws, size_t ws_size,
                              hipStream_t stream)
{
    const float* x     = (const float*)d_in[0];
    const float* w_ih0 = (const float*)d_in[1];
    const float* w_hh0 = (const float*)d_in[2];
    const float* b_ih0 = (const float*)d_in[3];
    const float* b_hh0 = (const float*)d_in[4];
    const float* w_ih1 = (const float*)d_in[5];
    const float* w_hh1 = (const float*)d_in[6];
    const float* b_ih1 = (const float*)d_in[7];
    const float* b_hh1 = (const float*)d_in[8];
    const float* fc_w  = (const float*)d_in[9];
    const float* fc_b  = (const float*)d_in[10];
    float* out = (float*)d_out;

    hipLaunchKernelGGL(gru_mfma, dim3(256), dim3(512), 0, stream,
                       x, w_ih0, w_hh0, b_ih0, b_hh0,
                       w_ih1, w_hh1, b_ih1, b_hh1, fc_w, fc_b, out);
}